// Round 8
// baseline (61.490 us; speedup 1.0000x reference)
//
#include <hip/hip_runtime.h>
#include <math.h>

// Problem constants: B=32, L=2048, F=512, K=128, LOUT=1921
#define BB 32
#define LL 2048
#define FF 512
#define KK 128
#define LOUT (LL - KK + 1)      // 1921
#define TC 62                   // rows per chunk (single chain)
#define NCH 31                  // chunks per batch: 31*62 = 1922 >= 1921
#define F4 (FF / 4)             // 128
#define PF 8                    // prefetch pipeline depth

// ---------------------------------------------------------------------------
// Kernel 1: tau[b,f] = sigmoid((x[b,L-1,:] . W[f,:] + bias[f]) / 10 - 3)
//           norm[b,f] = 1 / sum_{i=0..K-1} tau^i   (Horner)
//           tauK[b,f] = tau^K                       (7 squarings)
// ---------------------------------------------------------------------------
__global__ __launch_bounds__(128) void tau_kernel(const float* __restrict__ x,
                                                  const float* __restrict__ W,
                                                  const float* __restrict__ bias,
                                                  float* __restrict__ tau_out,
                                                  float* __restrict__ norm_out,
                                                  float* __restrict__ tauK_out) {
    __shared__ float feat[FF];
    const int b   = blockIdx.x >> 2;
    const int fq  = blockIdx.x & 3;
    const int tid = threadIdx.x;

    ((float4*)feat)[tid] =
        ((const float4*)(x + ((size_t)b * LL + (LL - 1)) * FF))[tid];
    __syncthreads();

    const int f = fq * 128 + tid;
    const float4* __restrict__ Wrow = (const float4*)(W + (size_t)f * FF);
    const float4* __restrict__ fv   = (const float4*)feat;

    float a0 = 0.f, a1 = 0.f, a2 = 0.f, a3 = 0.f;
#pragma unroll 4
    for (int j = 0; j < F4; j += 2) {
        float4 w0 = Wrow[j],     w1 = Wrow[j + 1];
        float4 x0 = fv[j],       x1 = fv[j + 1];
        a0 = fmaf(w0.x, x0.x, a0); a1 = fmaf(w0.y, x0.y, a1);
        a2 = fmaf(w0.z, x0.z, a2); a3 = fmaf(w0.w, x0.w, a3);
        a0 = fmaf(w1.x, x1.x, a0); a1 = fmaf(w1.y, x1.y, a1);
        a2 = fmaf(w1.z, x1.z, a2); a3 = fmaf(w1.w, x1.w, a3);
    }
    const float acc = (a0 + a1) + (a2 + a3);
    const float z   = (acc + bias[f]) * 0.1f - 3.0f;
    const float tau = 1.0f / (1.0f + expf(-z));

    float den = 1.0f;
#pragma unroll 8
    for (int i = 0; i < KK - 1; ++i) den = fmaf(den, tau, 1.0f);

    float tk = tau;
#pragma unroll
    for (int i = 0; i < 7; ++i) tk *= tk;

    const int idx = b * FF + f;
    tau_out[idx]  = tau;
    norm_out[idx] = 1.0f / den;
    tauK_out[idx] = tk;
}

// ---------------------------------------------------------------------------
// Kernel 2: single-chain, 8-deep manual prefetch pipeline.
// Grid = B*NCH blocks of 128 threads; thread (b,c,f4) owns chunk c: 62
// output rows. All reads form ONE contiguous row range
//   [t0+K-T, t0+K+nout-1)  (T = wave-uniform truncation length)
// walked by a single loop: S = fma(S,tau,row); store once r >= T-1.
// p[0..PF-1] is a rotating prefetch register file: p[j] written at step j,
// consumed 8 steps later -> structurally live -> compiler cannot collapse
// the pipeline (r5 lesson: sched_barrier gets defeated; live regs don't).
// Run-ahead loads are clamped to the last row of x[b] (in-bounds, unused).
// ---------------------------------------------------------------------------
__global__ __launch_bounds__(128) void fir_kernel(const float* __restrict__ x,
                                                  const float* __restrict__ tau_arr,
                                                  const float* __restrict__ norm_arr,
                                                  const float* __restrict__ tauK_arr,
                                                  float* __restrict__ out) {
    const int b  = blockIdx.x / NCH;
    const int c  = blockIdx.x % NCH;
    const int f4 = threadIdx.x;
    const int t0 = c * TC;
    const int nout = (t0 + TC <= LOUT) ? TC : (LOUT - t0);  // 62, last chunk 61

    const int idx4 = b * F4 + f4;
    const float4 tau = ((const float4*)tau_arr)[idx4];
    const float4 nrm = ((const float4*)norm_arr)[idx4];
    const float4 tk  = ((const float4*)tauK_arr)[idx4];

    const float4* __restrict__ xb = (const float4*)(x + (size_t)b * LL * FF) + f4;
    float4* __restrict__ ob = (float4*)(out + (size_t)b * LOUT * FF) + f4;

    // truncation length; taps beyond T contribute < 1e-14 (T=K for tau->1)
    const float tmax = fmaxf(fmaxf(tau.x, tau.y), fmaxf(tau.z, tau.w));
    int T = KK;
    if (tmax < 0.999f) {
        T = (int)ceilf(-32.236191f / logf(tmax));  // ln(1e-14)
        T = (T > KK) ? KK : (T < 4 ? 4 : T);
    }
    // wave-uniform T (extra taps only add accuracy; keeps stores converged)
#pragma unroll
    for (int off = 32; off; off >>= 1) {
        const int o = __shfl_xor(T, off);
        T = (o > T) ? o : T;
    }

    const bool fast =
        __all(tk.x == 0.f && tk.y == 0.f && tk.z == 0.f && tk.w == 0.f);

    if (fast) {
        const int base_t = t0 + KK - T;     // first row of the range
        const int nrows  = T + nout - 1;    // rows to consume
        const int oshift = T - 1;           // out[t0 + r - oshift] at step r

        float4 p[PF];
#pragma unroll
        for (int j = 0; j < PF; ++j) {
            int t = base_t + j;
            t = (t < LL - 1) ? t : (LL - 1);
            p[j] = xb[(size_t)t * F4];
        }

        float4 S = make_float4(0.f, 0.f, 0.f, 0.f);
        for (int rr = 0; rr < nrows; rr += PF) {
#pragma unroll
            for (int j = 0; j < PF; ++j) {
                const int r = rr + j;
                const float4 v = p[j];
                // refill slot j with row r+PF (clamped; junk rows land after
                // all stores are done, so the extra FMAs are harmless)
                int t = base_t + r + PF;
                t = (t < LL - 1) ? t : (LL - 1);
                p[j] = xb[(size_t)t * F4];

                S.x = fmaf(S.x, tau.x, v.x);
                S.y = fmaf(S.y, tau.y, v.y);
                S.z = fmaf(S.z, tau.z, v.z);
                S.w = fmaf(S.w, tau.w, v.w);

                if (r >= oshift && r < nrows) {  // wave-uniform predicate
                    ob[(size_t)(t0 + r - oshift) * F4] = make_float4(
                        nrm.x * S.x, nrm.y * S.y, nrm.z * S.z, nrm.w * S.w);
                }
            }
        }
    } else {
        // general sliding-window recurrence (correct for any tau):
        // full-K Horner warm-up, then S = tau*S + lead - tau^K * trail
        float4 S = make_float4(0.f, 0.f, 0.f, 0.f);
        for (int i = 0; i < KK; ++i) {
            const float4 v = xb[(size_t)(t0 + i) * F4];
            S.x = fmaf(S.x, tau.x, v.x);
            S.y = fmaf(S.y, tau.y, v.y);
            S.z = fmaf(S.z, tau.z, v.z);
            S.w = fmaf(S.w, tau.w, v.w);
        }
        ob[(size_t)t0 * F4] = make_float4(nrm.x * S.x, nrm.y * S.y,
                                          nrm.z * S.z, nrm.w * S.w);
        for (int k = 1; k < nout; ++k) {
            const float4 lead  = xb[(size_t)(t0 + k + KK - 1) * F4];
            const float4 trail = xb[(size_t)(t0 + k - 1) * F4];
            S.x = fmaf(S.x, tau.x, fmaf(-tk.x, trail.x, lead.x));
            S.y = fmaf(S.y, tau.y, fmaf(-tk.y, trail.y, lead.y));
            S.z = fmaf(S.z, tau.z, fmaf(-tk.z, trail.z, lead.z));
            S.w = fmaf(S.w, tau.w, fmaf(-tk.w, trail.w, lead.w));
            ob[(size_t)(t0 + k) * F4] = make_float4(
                nrm.x * S.x, nrm.y * S.y, nrm.z * S.z, nrm.w * S.w);
        }
    }
}

extern "C" void kernel_launch(void* const* d_in, const int* in_sizes, int n_in,
                              void* d_out, int out_size, void* d_ws, size_t ws_size,
                              hipStream_t stream) {
    const float* x    = (const float*)d_in[0];  // [B, L, F]
    const float* W    = (const float*)d_in[1];  // [F, F]
    const float* bias = (const float*)d_in[2];  // [F]
    float* out = (float*)d_out;                 // [B, LOUT, F]

    float* ws = (float*)d_ws;
    float* tau_arr  = ws;                 // [B*F]
    float* norm_arr = ws + BB * FF;       // [B*F]
    float* tauK_arr = ws + 2 * BB * FF;   // [B*F]

    tau_kernel<<<BB * 4, 128, 0, stream>>>(x, W, bias, tau_arr, norm_arr, tauK_arr);
    fir_kernel<<<BB * NCH, 128, 0, stream>>>(x, tau_arr, norm_arr, tauK_arr, out);
}

// Round 9
// 61.285 us; speedup vs baseline: 1.0033x; 1.0033x over previous
//
#include <hip/hip_runtime.h>
#include <math.h>

// Problem constants: B=32, L=2048, F=512, K=128, LOUT=1921
#define BB 32
#define LL 2048
#define FF 512
#define KK 128
#define LOUT (LL - KK + 1)      // 1921
#define TC 16                   // rows per chunk
#define NCH ((LOUT + TC - 1) / TC)   // 121 chunks per batch
#define F4 (FF / 4)             // 128

// ---------------------------------------------------------------------------
// Kernel 1: tau[b,f] = sigmoid((x[b,L-1,:] . W[f,:] + bias[f]) / 10 - 3)
//           norm[b,f] = 1 / sum_{i=0..K-1} tau^i   (Horner)
//           tauK[b,f] = tau^K                       (7 squarings)
// ---------------------------------------------------------------------------
__global__ __launch_bounds__(128) void tau_kernel(const float* __restrict__ x,
                                                  const float* __restrict__ W,
                                                  const float* __restrict__ bias,
                                                  float* __restrict__ tau_out,
                                                  float* __restrict__ norm_out,
                                                  float* __restrict__ tauK_out) {
    __shared__ float feat[FF];
    const int b   = blockIdx.x >> 2;
    const int fq  = blockIdx.x & 3;
    const int tid = threadIdx.x;

    ((float4*)feat)[tid] =
        ((const float4*)(x + ((size_t)b * LL + (LL - 1)) * FF))[tid];
    __syncthreads();

    const int f = fq * 128 + tid;
    const float4* __restrict__ Wrow = (const float4*)(W + (size_t)f * FF);
    const float4* __restrict__ fv   = (const float4*)feat;

    float a0 = 0.f, a1 = 0.f, a2 = 0.f, a3 = 0.f;
#pragma unroll 4
    for (int j = 0; j < F4; j += 2) {
        float4 w0 = Wrow[j],     w1 = Wrow[j + 1];
        float4 x0 = fv[j],       x1 = fv[j + 1];
        a0 = fmaf(w0.x, x0.x, a0); a1 = fmaf(w0.y, x0.y, a1);
        a2 = fmaf(w0.z, x0.z, a2); a3 = fmaf(w0.w, x0.w, a3);
        a0 = fmaf(w1.x, x1.x, a0); a1 = fmaf(w1.y, x1.y, a1);
        a2 = fmaf(w1.z, x1.z, a2); a3 = fmaf(w1.w, x1.w, a3);
    }
    const float acc = (a0 + a1) + (a2 + a3);
    const float z   = (acc + bias[f]) * 0.1f - 3.0f;
    const float tau = 1.0f / (1.0f + expf(-z));

    float den = 1.0f;
#pragma unroll 8
    for (int i = 0; i < KK - 1; ++i) den = fmaf(den, tau, 1.0f);

    float tk = tau;
#pragma unroll
    for (int i = 0; i < 7; ++i) tk *= tk;

    const int idx = b * FF + f;
    tau_out[idx]  = tau;
    norm_out[idx] = 1.0f / den;
    tauK_out[idx] = tk;
}

// ---------------------------------------------------------------------------
// Kernel 2: TLP + low-amp version. Grid = B*NCH = 3872 blocks of 128
// threads (~30 waves/CU -- r6 proved the chip services ~6.5 TB/s of
// logical traffic at this occupancy). Chunk = 16 rows; warm-up uses a
// 1e-7 tap cutoff: T = ceil(-16.118/ln tau) ~ 6 for this data's tau~0.05
// (truncation error ~5e-7 << 0.104 threshold; clamps to full K as
// tau->1, so correct for any input). Read amp = (T+15)/16 ~ 1.31.
// Plain stores (NT stores raised FETCH in r4-r6).
//   warm-up: S = fma(S, tau, x[t0+i]),  i in [K-T, K)
//   steady : S = fma(S, tau, x[t+K-1]); out[t] = norm*S   (15 iters)
// ---------------------------------------------------------------------------
__global__ __launch_bounds__(128) void fir_kernel(const float* __restrict__ x,
                                                  const float* __restrict__ tau_arr,
                                                  const float* __restrict__ norm_arr,
                                                  const float* __restrict__ tauK_arr,
                                                  float* __restrict__ out) {
    const int b  = blockIdx.x / NCH;
    const int c  = blockIdx.x % NCH;
    const int f4 = threadIdx.x;
    const int t0 = c * TC;
    const int nout = (t0 + TC <= LOUT) ? TC : (LOUT - t0);  // 16; last chunk 1

    const int idx4 = b * F4 + f4;
    const float4 tau = ((const float4*)tau_arr)[idx4];
    const float4 nrm = ((const float4*)norm_arr)[idx4];
    const float4 tk  = ((const float4*)tauK_arr)[idx4];

    const float4* __restrict__ xb = (const float4*)(x + (size_t)b * LL * FF) + f4;
    float4* __restrict__ ob = (float4*)(out + (size_t)b * LOUT * FF) + f4;

    // truncation length from 1e-7 tap cutoff (clamped to K for tau->1)
    const float tmax = fmaxf(fmaxf(tau.x, tau.y), fmaxf(tau.z, tau.w));
    int T = KK;
    if (tmax < 0.999f) {
        T = (int)ceilf(-16.118096f / logf(tmax));  // ln(1e-7)
        T = (T > KK) ? KK : (T < 2 ? 2 : T);
    }
    // wave-uniform T (extra taps only add accuracy; keeps lanes converged)
#pragma unroll
    for (int off = 32; off; off >>= 1) {
        const int o = __shfl_xor(T, off);
        T = (o > T) ? o : T;
    }

    // ---- warm-up: Horner over last T taps of window at t0 ----
    float4 S = make_float4(0.f, 0.f, 0.f, 0.f);
    for (int i = KK - T; i < KK; ++i) {
        const float4 v = xb[(size_t)(t0 + i) * F4];
        S.x = fmaf(S.x, tau.x, v.x);
        S.y = fmaf(S.y, tau.y, v.y);
        S.z = fmaf(S.z, tau.z, v.z);
        S.w = fmaf(S.w, tau.w, v.w);
    }
    ob[(size_t)t0 * F4] =
        make_float4(nrm.x * S.x, nrm.y * S.y, nrm.z * S.z, nrm.w * S.w);

    const bool fast =
        __all(tk.x == 0.f && tk.y == 0.f && tk.z == 0.f && tk.w == 0.f);

    if (fast) {
        if (nout == TC) {
#pragma unroll
            for (int k = 1; k < TC; ++k) {
                const int t = t0 + k;
                const float4 v = xb[(size_t)(t + KK - 1) * F4];
                S.x = fmaf(S.x, tau.x, v.x);
                S.y = fmaf(S.y, tau.y, v.y);
                S.z = fmaf(S.z, tau.z, v.z);
                S.w = fmaf(S.w, tau.w, v.w);
                ob[(size_t)t * F4] = make_float4(
                    nrm.x * S.x, nrm.y * S.y, nrm.z * S.z, nrm.w * S.w);
            }
        } else {
            for (int k = 1; k < nout; ++k) {
                const int t = t0 + k;
                const float4 v = xb[(size_t)(t + KK - 1) * F4];
                S.x = fmaf(S.x, tau.x, v.x);
                S.y = fmaf(S.y, tau.y, v.y);
                S.z = fmaf(S.z, tau.z, v.z);
                S.w = fmaf(S.w, tau.w, v.w);
                ob[(size_t)t * F4] = make_float4(
                    nrm.x * S.x, nrm.y * S.y, nrm.z * S.z, nrm.w * S.w);
            }
        }
    } else {
        // general sliding-window recurrence (correct for any tau)
        for (int k = 1; k < nout; ++k) {
            const int t = t0 + k;
            const float4 lead  = xb[(size_t)(t + KK - 1) * F4];
            const float4 trail = xb[(size_t)(t - 1) * F4];
            S.x = fmaf(S.x, tau.x, fmaf(-tk.x, trail.x, lead.x));
            S.y = fmaf(S.y, tau.y, fmaf(-tk.y, trail.y, lead.y));
            S.z = fmaf(S.z, tau.z, fmaf(-tk.z, trail.z, lead.z));
            S.w = fmaf(S.w, tau.w, fmaf(-tk.w, trail.w, lead.w));
            ob[(size_t)t * F4] = make_float4(
                nrm.x * S.x, nrm.y * S.y, nrm.z * S.z, nrm.w * S.w);
        }
    }
}

extern "C" void kernel_launch(void* const* d_in, const int* in_sizes, int n_in,
                              void* d_out, int out_size, void* d_ws, size_t ws_size,
                              hipStream_t stream) {
    const float* x    = (const float*)d_in[0];  // [B, L, F]
    const float* W    = (const float*)d_in[1];  // [F, F]
    const float* bias = (const float*)d_in[2];  // [F]
    float* out = (float*)d_out;                 // [B, LOUT, F]

    float* ws = (float*)d_ws;
    float* tau_arr  = ws;                 // [B*F]
    float* norm_arr = ws + BB * FF;       // [B*F]
    float* tauK_arr = ws + 2 * BB * FF;   // [B*F]

    tau_kernel<<<BB * 4, 128, 0, stream>>>(x, W, bias, tau_arr, norm_arr, tauK_arr);
    fir_kernel<<<BB * NCH, 128, 0, stream>>>(x, tau_arr, norm_arr, tauK_arr, out);
}